// Round 4
// baseline (715.801 us; speedup 1.0000x reference)
//
#include <hip/hip_runtime.h>
#include <hip/hip_bf16.h>
#include <cstdint>

// Encoder_Decoder: C=80 classes, H=128, N=sum(lengths)=20640, L_max=416.
// Phases:
//  1) concat extras into allf[:,128:224]
//  2) feat = relu(acbf @ appear_W^T + ab) -> allf[:, :128]   (GEMM K=1024)
//  3) dec  = relu(allf @ feat_W^T + fb)                      (GEMM K=224)
//  4) xp[d][start+t][g] = dec[gathered row] @ Wih[c,d]^T + bih   (per-class GEMM K=128)
//  5) GRU scan per (class, dir): 128 thr x 3 rows, f16 weights in VGPRs + v_dot2,
//     LDS-only barrier (no vmcnt drain), 2-step-deep x prefetch
//  6) out[n] = sigmoid(dot(outY[n,:256], out_W) + out_b)

typedef _Float16 half2_t __attribute__((ext_vector_type(2)));
typedef _Float16 half8_t __attribute__((ext_vector_type(8)));

// Workgroup barrier that orders ONLY LDS traffic. __syncthreads() forces
// `s_waitcnt vmcnt(0) expcnt(0) lgkmcnt(0)` before s_barrier, which drains
// in-flight global prefetch loads/stores every GRU step (~900 cyc HBM latency
// paid per step — R3's 1750 cyc/step). Cross-thread data here flows only
// through LDS, so lgkmcnt(0) is sufficient.
__device__ __forceinline__ void lds_barrier() {
    asm volatile("s_waitcnt lgkmcnt(0)\n\ts_barrier" ::: "memory");
}

// ---------------- 1. concat extras ----------------
__global__ __launch_bounds__(256) void concat_kernel(
    const float* __restrict__ score, const float* __restrict__ box,
    const float* __restrict__ orig, float* __restrict__ allf, int N)
{
    int idx = blockIdx.x * 256 + threadIdx.x;
    int total = N * 96;
    if (idx >= total) return;
    int n = idx / 96, j = idx - n * 96;
    float v;
    if (j < 32)      v = score[(size_t)n * 32 + j];
    else if (j < 64) v = box  [(size_t)n * 32 + j - 32];
    else             v = orig [(size_t)n * 32 + j - 64];
    allf[(size_t)n * 224 + 128 + j] = v;
}

// ---------------- generic fp32 GEMM: C(N x 128) = act(A(N x K) * B(128 x K)^T + bias) ----------------
__global__ __launch_bounds__(256) void gemm128_kernel(
    const float* __restrict__ A, int lda,
    const float* __restrict__ B,            // 128 x K row-major
    const float* __restrict__ bias,
    float* __restrict__ Cc, int ldc,
    int N, int K, int do_relu)
{
    __shared__ __align__(16) float As[16][64];
    __shared__ __align__(16) float Bs[16][128];
    const int tid = threadIdx.x;
    const int tx = tid & 15, ty = tid >> 4;
    const int n0 = blockIdx.x * 64;
    const int arow = tid >> 2;

    float acc[4][8] = {};

    int ar = n0 + arow; if (ar > N - 1) ar = N - 1;
    const float* Aptr  = A + (size_t)ar * lda + (tid & 3) * 4;
    const int m0 = tid >> 2;                 // 0..63
    const int kq4 = (tid & 3) * 4;
    const float* Bptr0 = B + (size_t)m0 * K + (tid & 3) * 4;
    const float* Bptr1 = Bptr0 + (size_t)64 * K;

    float4 av = *(const float4*)(Aptr);
    float4 b0 = *(const float4*)(Bptr0);
    float4 b1 = *(const float4*)(Bptr1);

    for (int kb = 0; kb < K; kb += 16) {
        lds_barrier();   // previous compute's LDS reads done before overwrite
        As[kq4 + 0][arow] = av.x;
        As[kq4 + 1][arow] = av.y;
        As[kq4 + 2][arow] = av.z;
        As[kq4 + 3][arow] = av.w;
        Bs[kq4 + 0][m0] = b0.x; Bs[kq4 + 1][m0] = b0.y;
        Bs[kq4 + 2][m0] = b0.z; Bs[kq4 + 3][m0] = b0.w;
        Bs[kq4 + 0][m0 + 64] = b1.x; Bs[kq4 + 1][m0 + 64] = b1.y;
        Bs[kq4 + 2][m0 + 64] = b1.z; Bs[kq4 + 3][m0 + 64] = b1.w;
        lds_barrier();
        if (kb + 16 < K) {     // prefetch next tile; latency hidden under compute
            av = *(const float4*)(Aptr + kb + 16);
            b0 = *(const float4*)(Bptr0 + kb + 16);
            b1 = *(const float4*)(Bptr1 + kb + 16);
        }
        #pragma unroll
        for (int kk = 0; kk < 16; kk++) {
            float4 a = *(const float4*)&As[kk][ty * 4];
            float4 p = *(const float4*)&Bs[kk][tx * 8];
            float4 q = *(const float4*)&Bs[kk][tx * 8 + 4];
            float av4[4] = {a.x, a.y, a.z, a.w};
            float bv[8]  = {p.x, p.y, p.z, p.w, q.x, q.y, q.z, q.w};
            #pragma unroll
            for (int i = 0; i < 4; i++)
                #pragma unroll
                for (int j = 0; j < 8; j++)
                    acc[i][j] = fmaf(av4[i], bv[j], acc[i][j]);
        }
    }

    #pragma unroll
    for (int i = 0; i < 4; i++) {
        int row = n0 + ty * 4 + i;
        if (row >= N) continue;
        float o[8];
        #pragma unroll
        for (int j = 0; j < 8; j++) {
            float v = acc[i][j] + bias[tx * 8 + j];
            if (do_relu) v = v > 0.f ? v : 0.f;
            o[j] = v;
        }
        float4* dst = (float4*)(Cc + (size_t)row * ldc + tx * 8);
        dst[0] = make_float4(o[0], o[1], o[2], o[3]);
        dst[1] = make_float4(o[4], o[5], o[6], o[7]);
    }
}

// ---------------- 4. Xp per-class GEMM (K=128) with direction-dependent row gather ----------------
__global__ __launch_bounds__(256) void xp_kernel(
    const float* __restrict__ dec,    // N x 128
    const float* __restrict__ Wih,    // C x 2 x 384 x 128
    const float* __restrict__ bih,    // C x 2 x 384
    const int* __restrict__ ucl,      // C+1
    float* __restrict__ xp,           // 2 x N x 384
    int N)
{
    const int c = blockIdx.x;
    const int tile = blockIdx.y;
    const int d  = blockIdx.z / 3;
    const int mt = blockIdx.z % 3;
    const int start = ucl[c];
    const int len = ucl[c + 1] - start;
    const int t0 = tile * 64;
    if (t0 >= len) return;

    __shared__ __align__(16) float As[16][64];
    __shared__ __align__(16) float Bs[16][128];
    const int tid = threadIdx.x;
    const int tx = tid & 15, ty = tid >> 4;
    const int arow = tid >> 2;

    int t = t0 + arow; if (t > len - 1) t = len - 1;
    int srow = start + (d ? (len - 1 - t) : t);
    const float* Aptr = dec + (size_t)srow * 128 + (tid & 3) * 4;

    const float* Bbase = Wih + ((size_t)(c * 2 + d) * 384 + mt * 128) * 128;
    const int m0 = tid >> 2;
    const int kq4 = (tid & 3) * 4;
    const float* Bptr0 = Bbase + (size_t)m0 * 128 + (tid & 3) * 4;
    const float* Bptr1 = Bptr0 + (size_t)64 * 128;

    float4 av = *(const float4*)(Aptr);
    float4 b0 = *(const float4*)(Bptr0);
    float4 b1 = *(const float4*)(Bptr1);

    float acc[4][8] = {};
    for (int kb = 0; kb < 128; kb += 16) {
        lds_barrier();
        As[kq4 + 0][arow] = av.x;
        As[kq4 + 1][arow] = av.y;
        As[kq4 + 2][arow] = av.z;
        As[kq4 + 3][arow] = av.w;
        Bs[kq4 + 0][m0] = b0.x; Bs[kq4 + 1][m0] = b0.y;
        Bs[kq4 + 2][m0] = b0.z; Bs[kq4 + 3][m0] = b0.w;
        Bs[kq4 + 0][m0 + 64] = b1.x; Bs[kq4 + 1][m0 + 64] = b1.y;
        Bs[kq4 + 2][m0 + 64] = b1.z; Bs[kq4 + 3][m0 + 64] = b1.w;
        lds_barrier();
        if (kb + 16 < 128) {
            av = *(const float4*)(Aptr + kb + 16);
            b0 = *(const float4*)(Bptr0 + kb + 16);
            b1 = *(const float4*)(Bptr1 + kb + 16);
        }
        #pragma unroll
        for (int kk = 0; kk < 16; kk++) {
            float4 a = *(const float4*)&As[kk][ty * 4];
            float4 p = *(const float4*)&Bs[kk][tx * 8];
            float4 q = *(const float4*)&Bs[kk][tx * 8 + 4];
            float av4[4] = {a.x, a.y, a.z, a.w};
            float bv[8]  = {p.x, p.y, p.z, p.w, q.x, q.y, q.z, q.w};
            #pragma unroll
            for (int i = 0; i < 4; i++)
                #pragma unroll
                for (int j = 0; j < 8; j++)
                    acc[i][j] = fmaf(av4[i], bv[j], acc[i][j]);
        }
    }

    const float* bias = bih + (size_t)(c * 2 + d) * 384 + mt * 128;
    #pragma unroll
    for (int i = 0; i < 4; i++) {
        int tt = t0 + ty * 4 + i;
        if (tt >= len) continue;
        float o[8];
        #pragma unroll
        for (int j = 0; j < 8; j++) o[j] = acc[i][j] + bias[tx * 8 + j];
        float4* dst = (float4*)(xp + ((size_t)d * N + start + tt) * 384 + mt * 128 + tx * 8);
        dst[0] = make_float4(o[0], o[1], o[2], o[3]);
        dst[1] = make_float4(o[4], o[5], o[6], o[7]);
    }
}

// ---------------- 5. GRU scan ----------------
// One block per (class,dir), 128 threads. Thread g owns gate rows {g, g+128, g+256}.
// f16 weights in 192 VGPRs, v_dot2_f32_f16 matvec, h exchanged via 512B LDS
// double-buffer. lds_barrier() (lgkmcnt-only) keeps global x loads / outY
// stores in flight across steps; 2x-unrolled loop gives the x prefetch a
// 2-step-deep pipeline (wait lands ~1400 cyc after issue > ~900 cyc HBM miss).
__global__ __launch_bounds__(128, 1) void gru_kernel(
    const float* __restrict__ xp,     // 2 x N x 384
    const float* __restrict__ Whh,    // C x 2 x 384 x 128
    const float* __restrict__ bhh,    // C x 2 x 384
    const int* __restrict__ ucl,
    float* __restrict__ outY,         // N x 256
    int N)
{
    const int c = blockIdx.x, d = blockIdx.y;
    const int start = ucl[c];
    const int len = ucl[c + 1] - start;
    const int g = threadIdx.x;        // 0..127

    const float* wbase = Whh + (size_t)(c * 2 + d) * 384 * 128;
    half2_t w0[64], w1[64], w2[64];
    {
        const float2* r0 = (const float2*)(wbase + (size_t)g * 128);
        const float2* r1 = (const float2*)(wbase + (size_t)(g + 128) * 128);
        const float2* r2 = (const float2*)(wbase + (size_t)(g + 256) * 128);
        #pragma unroll
        for (int i = 0; i < 64; i++) {
            float2 a = r0[i];
            w0[i] = half2_t{(_Float16)a.x, (_Float16)a.y};
        }
        #pragma unroll
        for (int i = 0; i < 64; i++) {
            float2 a = r1[i];
            w1[i] = half2_t{(_Float16)a.x, (_Float16)a.y};
        }
        #pragma unroll
        for (int i = 0; i < 64; i++) {
            float2 a = r2[i];
            w2[i] = half2_t{(_Float16)a.x, (_Float16)a.y};
        }
    }
    const float* bb = bhh + (size_t)(c * 2 + d) * 384;
    const float bh0 = bb[g], bh1 = bb[g + 128], bh2 = bb[g + 256];

    __shared__ __align__(16) half2_t hbuf[2][64];
    if (g < 64) { hbuf[0][g] = half2_t{(_Float16)0.f, (_Float16)0.f}; }
    const float* xpb = xp + ((size_t)d * N + start) * 384;
    float* outb = outY + (size_t)start * 256 + d * 128;

    // x pipeline: xa = x(t even), xb = x(t odd)
    float xa0 = xpb[g], xa1 = xpb[g + 128], xa2 = xpb[g + 256];
    const size_t o1 = (size_t)((len > 1) ? 1 : 0) * 384;
    float xb0 = xpb[o1 + g], xb1 = xpb[o1 + g + 128], xb2 = xpb[o1 + g + 256];
    float hcur = 0.f;
    lds_barrier();

#define GRU_SUBSTEP(HP_IDX, HN_IDX, X0, X1, X2, TT)                          \
    {                                                                        \
        const half8_t* __restrict__ hp = (const half8_t*)hbuf[HP_IDX];       \
        _Float16* __restrict__ hn = (_Float16*)hbuf[HN_IDX];                 \
        float a0 = bh0, a1 = bh1, a2 = bh2;                                  \
        _Pragma("unroll")                                                    \
        for (int i = 0; i < 16; i++) {                                       \
            union { half8_t v; half2_t h2[4]; } u;                           \
            u.v = hp[i];                                                     \
            _Pragma("unroll")                                                \
            for (int j = 0; j < 4; j++) {                                    \
                a0 = __builtin_amdgcn_fdot2(w0[i * 4 + j], u.h2[j], a0, false);\
                a1 = __builtin_amdgcn_fdot2(w1[i * 4 + j], u.h2[j], a1, false);\
                a2 = __builtin_amdgcn_fdot2(w2[i * 4 + j], u.h2[j], a2, false);\
            }                                                                \
        }                                                                    \
        float r = __fdividef(1.f, 1.f + __expf(-((X0) + a0)));               \
        float z = __fdividef(1.f, 1.f + __expf(-((X1) + a1)));               \
        float pre = (X2) + r * a2;                                           \
        float n = 1.f - __fdividef(2.f, __expf(2.f * pre) + 1.f);            \
        float hnew = (1.f - z) * n + z * hcur;                               \
        hn[g] = (_Float16)hnew;                                              \
        hcur = hnew;                                                         \
        outb[(size_t)(TT) * 256 + g] = hnew;                                 \
    }

    for (int t = 0; t < len; t += 2) {
        // ---- sub-step A: time t (even) ----
        int tpa = (t + 2 < len) ? (t + 2) : (len - 1);
        const float* xra = xpb + (size_t)tpa * 384;
        float ta0 = xra[g], ta1 = xra[g + 128], ta2 = xra[g + 256];
        int ttA = d ? (len - 1 - t) : t;
        GRU_SUBSTEP(0, 1, xa0, xa1, xa2, ttA)
        xa0 = ta0; xa1 = ta1; xa2 = ta2;   // wait for x(t+2) lands at first use, 2 steps after issue
        lds_barrier();
        if (t + 1 >= len) break;
        // ---- sub-step B: time t+1 (odd) ----
        int tpb = (t + 3 < len) ? (t + 3) : (len - 1);
        const float* xrb = xpb + (size_t)tpb * 384;
        float tb0 = xrb[g], tb1 = xrb[g + 128], tb2 = xrb[g + 256];
        int ttB = d ? (len - 2 - t) : (t + 1);
        GRU_SUBSTEP(1, 0, xb0, xb1, xb2, ttB)
        xb0 = tb0; xb1 = tb1; xb2 = tb2;
        lds_barrier();
    }
#undef GRU_SUBSTEP
}

// ---------------- 6. head: sigmoid(dot(outY[n], out_W) + b) ----------------
__global__ __launch_bounds__(256) void final_kernel(
    const float* __restrict__ outY,   // N x 256
    const float* __restrict__ outW,   // 256
    const float* __restrict__ outb,   // 1
    float* __restrict__ out, int N)
{
    __shared__ __align__(16) float wsh[256];
    wsh[threadIdx.x] = outW[threadIdx.x];
    __syncthreads();
    const int lane = threadIdx.x & 63;
    const int wave = (blockIdx.x * 256 + threadIdx.x) >> 6;
    const int nw = gridDim.x * 4;
    float4 w4 = *(const float4*)&wsh[lane * 4];
    float b = outb[0];
    for (int n = wave; n < N; n += nw) {
        float4 y = *(const float4*)(outY + (size_t)n * 256 + lane * 4);
        float p = y.x * w4.x + y.y * w4.y + y.z * w4.z + y.w * w4.w;
        #pragma unroll
        for (int off = 32; off > 0; off >>= 1) p += __shfl_down(p, off);
        if (lane == 0) out[n] = 1.f / (1.f + __expf(-(p + b)));
    }
}

extern "C" void kernel_launch(void* const* d_in, const int* in_sizes, int n_in,
                              void* d_out, int out_size, void* d_ws, size_t ws_size,
                              hipStream_t stream)
{
    const float* acbf  = (const float*)d_in[3];
    const float* score = (const float*)d_in[4];
    const float* box   = (const float*)d_in[5];
    const float* orig  = (const float*)d_in[6];
    const int*   ucl   = (const int*)d_in[8];
    const float* aW  = (const float*)d_in[9];
    const float* ab  = (const float*)d_in[10];
    const float* fW  = (const float*)d_in[11];
    const float* fb  = (const float*)d_in[12];
    const float* Wih = (const float*)d_in[13];
    const float* Whh = (const float*)d_in[14];
    const float* bih = (const float*)d_in[15];
    const float* bhh = (const float*)d_in[16];
    const float* oW  = (const float*)d_in[17];
    const float* ob  = (const float*)d_in[18];
    float* out = (float*)d_out;

    const int N = in_sizes[3] / 1024;   // 20640
    const int C = in_sizes[7];          // 80

    // workspace layout (floats): allf N*224 | dec N*128 | xp 2*N*384  (~92.5 MB)
    // outY (N*256) overlaps allf+dec head — both dead once the GRU starts.
    float* ws   = (float*)d_ws;
    float* allf = ws;
    float* dec  = ws + (size_t)N * 224;
    float* xp   = dec + (size_t)N * 128;
    float* outY = ws;

    dim3 blk(256);
    concat_kernel<<<dim3((N * 96 + 255) / 256), blk, 0, stream>>>(score, box, orig, allf, N);
    gemm128_kernel<<<dim3((N + 63) / 64), blk, 0, stream>>>(acbf, 1024, aW, ab, allf, 224, N, 1024, 1);
    gemm128_kernel<<<dim3((N + 63) / 64), blk, 0, stream>>>(allf, 224, fW, fb, dec, 128, N, 224, 1);
    xp_kernel<<<dim3(C, 7, 6), blk, 0, stream>>>(dec, Wih, bih, ucl, xp, N);
    gru_kernel<<<dim3(C, 2), dim3(128), 0, stream>>>(xp, Whh, bhh, ucl, outY, N);
    final_kernel<<<dim3(160), blk, 0, stream>>>(outY, oW, ob, out, N);
}

// Round 5
// 695.310 us; speedup vs baseline: 1.0295x; 1.0295x over previous
//
#include <hip/hip_runtime.h>
#include <hip/hip_bf16.h>
#include <cstdint>

// Encoder_Decoder: C=80 classes, H=128, N=sum(lengths)=20640, L_max=416.
// Phases:
//  1) concat extras into allf[:,128:224]
//  2) feat = relu(acbf @ appear_W^T + ab) -> allf[:, :128]   (GEMM K=1024)
//  3) dec  = relu(allf @ feat_W^T + fb)                      (GEMM K=224)
//  4) xp[d][start+t][g] = dec[gathered row] @ Wih[c,d]^T + bih   (per-class GEMM K=128)
//  5) GRU scan per (class, dir): 128 thr x 3 rows, f16 weights in VGPRs + v_dot2,
//     LDS-only barrier, rolling 4-deep LDS->reg h prefetch window
//  6) out[n] = sigmoid(dot(outY[n,:256], out_W) + out_b)

typedef _Float16 half2_t __attribute__((ext_vector_type(2)));
typedef _Float16 half8_t __attribute__((ext_vector_type(8)));

// Workgroup barrier that orders ONLY LDS traffic (keeps global loads/stores
// in flight across GRU steps). Cross-thread data flows only through LDS.
__device__ __forceinline__ void lds_barrier() {
    asm volatile("s_waitcnt lgkmcnt(0)\n\ts_barrier" ::: "memory");
}

// ---------------- 1. concat extras ----------------
__global__ __launch_bounds__(256) void concat_kernel(
    const float* __restrict__ score, const float* __restrict__ box,
    const float* __restrict__ orig, float* __restrict__ allf, int N)
{
    int idx = blockIdx.x * 256 + threadIdx.x;
    int total = N * 96;
    if (idx >= total) return;
    int n = idx / 96, j = idx - n * 96;
    float v;
    if (j < 32)      v = score[(size_t)n * 32 + j];
    else if (j < 64) v = box  [(size_t)n * 32 + j - 32];
    else             v = orig [(size_t)n * 32 + j - 64];
    allf[(size_t)n * 224 + 128 + j] = v;
}

// ---------------- generic fp32 GEMM: C(N x 128) = act(A(N x K) * B(128 x K)^T + bias) ----------------
__global__ __launch_bounds__(256) void gemm128_kernel(
    const float* __restrict__ A, int lda,
    const float* __restrict__ B,            // 128 x K row-major
    const float* __restrict__ bias,
    float* __restrict__ Cc, int ldc,
    int N, int K, int do_relu)
{
    __shared__ __align__(16) float As[16][64];
    __shared__ __align__(16) float Bs[16][128];
    const int tid = threadIdx.x;
    const int tx = tid & 15, ty = tid >> 4;
    const int n0 = blockIdx.x * 64;
    const int arow = tid >> 2;

    float acc[4][8] = {};

    int ar = n0 + arow; if (ar > N - 1) ar = N - 1;
    const float* Aptr  = A + (size_t)ar * lda + (tid & 3) * 4;
    const int m0 = tid >> 2;                 // 0..63
    const int kq4 = (tid & 3) * 4;
    const float* Bptr0 = B + (size_t)m0 * K + (tid & 3) * 4;
    const float* Bptr1 = Bptr0 + (size_t)64 * K;

    float4 av = *(const float4*)(Aptr);
    float4 b0 = *(const float4*)(Bptr0);
    float4 b1 = *(const float4*)(Bptr1);

    for (int kb = 0; kb < K; kb += 16) {
        lds_barrier();   // previous compute's LDS reads done before overwrite
        As[kq4 + 0][arow] = av.x;
        As[kq4 + 1][arow] = av.y;
        As[kq4 + 2][arow] = av.z;
        As[kq4 + 3][arow] = av.w;
        Bs[kq4 + 0][m0] = b0.x; Bs[kq4 + 1][m0] = b0.y;
        Bs[kq4 + 2][m0] = b0.z; Bs[kq4 + 3][m0] = b0.w;
        Bs[kq4 + 0][m0 + 64] = b1.x; Bs[kq4 + 1][m0 + 64] = b1.y;
        Bs[kq4 + 2][m0 + 64] = b1.z; Bs[kq4 + 3][m0 + 64] = b1.w;
        lds_barrier();
        if (kb + 16 < K) {     // prefetch next tile; latency hidden under compute
            av = *(const float4*)(Aptr + kb + 16);
            b0 = *(const float4*)(Bptr0 + kb + 16);
            b1 = *(const float4*)(Bptr1 + kb + 16);
        }
        #pragma unroll
        for (int kk = 0; kk < 16; kk++) {
            float4 a = *(const float4*)&As[kk][ty * 4];
            float4 p = *(const float4*)&Bs[kk][tx * 8];
            float4 q = *(const float4*)&Bs[kk][tx * 8 + 4];
            float av4[4] = {a.x, a.y, a.z, a.w};
            float bv[8]  = {p.x, p.y, p.z, p.w, q.x, q.y, q.z, q.w};
            #pragma unroll
            for (int i = 0; i < 4; i++)
                #pragma unroll
                for (int j = 0; j < 8; j++)
                    acc[i][j] = fmaf(av4[i], bv[j], acc[i][j]);
        }
    }

    #pragma unroll
    for (int i = 0; i < 4; i++) {
        int row = n0 + ty * 4 + i;
        if (row >= N) continue;
        float o[8];
        #pragma unroll
        for (int j = 0; j < 8; j++) {
            float v = acc[i][j] + bias[tx * 8 + j];
            if (do_relu) v = v > 0.f ? v : 0.f;
            o[j] = v;
        }
        float4* dst = (float4*)(Cc + (size_t)row * ldc + tx * 8);
        dst[0] = make_float4(o[0], o[1], o[2], o[3]);
        dst[1] = make_float4(o[4], o[5], o[6], o[7]);
    }
}

// ---------------- 4. Xp per-class GEMM (K=128) with direction-dependent row gather ----------------
__global__ __launch_bounds__(256) void xp_kernel(
    const float* __restrict__ dec,    // N x 128
    const float* __restrict__ Wih,    // C x 2 x 384 x 128
    const float* __restrict__ bih,    // C x 2 x 384
    const int* __restrict__ ucl,      // C+1
    float* __restrict__ xp,           // 2 x N x 384
    int N)
{
    const int c = blockIdx.x;
    const int tile = blockIdx.y;
    const int d  = blockIdx.z / 3;
    const int mt = blockIdx.z % 3;
    const int start = ucl[c];
    const int len = ucl[c + 1] - start;
    const int t0 = tile * 64;
    if (t0 >= len) return;

    __shared__ __align__(16) float As[16][64];
    __shared__ __align__(16) float Bs[16][128];
    const int tid = threadIdx.x;
    const int tx = tid & 15, ty = tid >> 4;
    const int arow = tid >> 2;

    int t = t0 + arow; if (t > len - 1) t = len - 1;
    int srow = start + (d ? (len - 1 - t) : t);
    const float* Aptr = dec + (size_t)srow * 128 + (tid & 3) * 4;

    const float* Bbase = Wih + ((size_t)(c * 2 + d) * 384 + mt * 128) * 128;
    const int m0 = tid >> 2;
    const int kq4 = (tid & 3) * 4;
    const float* Bptr0 = Bbase + (size_t)m0 * 128 + (tid & 3) * 4;
    const float* Bptr1 = Bptr0 + (size_t)64 * 128;

    float4 av = *(const float4*)(Aptr);
    float4 b0 = *(const float4*)(Bptr0);
    float4 b1 = *(const float4*)(Bptr1);

    float acc[4][8] = {};
    for (int kb = 0; kb < 128; kb += 16) {
        lds_barrier();
        As[kq4 + 0][arow] = av.x;
        As[kq4 + 1][arow] = av.y;
        As[kq4 + 2][arow] = av.z;
        As[kq4 + 3][arow] = av.w;
        Bs[kq4 + 0][m0] = b0.x; Bs[kq4 + 1][m0] = b0.y;
        Bs[kq4 + 2][m0] = b0.z; Bs[kq4 + 3][m0] = b0.w;
        Bs[kq4 + 0][m0 + 64] = b1.x; Bs[kq4 + 1][m0 + 64] = b1.y;
        Bs[kq4 + 2][m0 + 64] = b1.z; Bs[kq4 + 3][m0 + 64] = b1.w;
        lds_barrier();
        if (kb + 16 < 128) {
            av = *(const float4*)(Aptr + kb + 16);
            b0 = *(const float4*)(Bptr0 + kb + 16);
            b1 = *(const float4*)(Bptr1 + kb + 16);
        }
        #pragma unroll
        for (int kk = 0; kk < 16; kk++) {
            float4 a = *(const float4*)&As[kk][ty * 4];
            float4 p = *(const float4*)&Bs[kk][tx * 8];
            float4 q = *(const float4*)&Bs[kk][tx * 8 + 4];
            float av4[4] = {a.x, a.y, a.z, a.w};
            float bv[8]  = {p.x, p.y, p.z, p.w, q.x, q.y, q.z, q.w};
            #pragma unroll
            for (int i = 0; i < 4; i++)
                #pragma unroll
                for (int j = 0; j < 8; j++)
                    acc[i][j] = fmaf(av4[i], bv[j], acc[i][j]);
        }
    }

    const float* bias = bih + (size_t)(c * 2 + d) * 384 + mt * 128;
    #pragma unroll
    for (int i = 0; i < 4; i++) {
        int tt = t0 + ty * 4 + i;
        if (tt >= len) continue;
        float o[8];
        #pragma unroll
        for (int j = 0; j < 8; j++) o[j] = acc[i][j] + bias[tx * 8 + j];
        float4* dst = (float4*)(xp + ((size_t)d * N + start + tt) * 384 + mt * 128 + tx * 8);
        dst[0] = make_float4(o[0], o[1], o[2], o[3]);
        dst[1] = make_float4(o[4], o[5], o[6], o[7]);
    }
}

// ---------------- 5. GRU scan ----------------
// One block per (class,dir), 128 threads. Thread g owns gate rows {g, g+128, g+256}.
// f16 weights in 192 VGPRs. R4 analysis: 1685 cyc/step with ~1100 cyc of exposed
// ds_read latency (no VGPR headroom to batch the 16 h-chunk reads). Fix: rolling
// 4-deep register window hr[4] (16 VGPRs) — consume hr[i&3], immediately reload
// with chunk i+4, so 4 LDS reads stay in flight (~96 cyc of dot2 between issue
// and use covers the ~120 cyc ds_read latency). Total ~238 VGPR < 256 cap.
__global__ __launch_bounds__(128, 1) void gru_kernel(
    const float* __restrict__ xp,     // 2 x N x 384
    const float* __restrict__ Whh,    // C x 2 x 384 x 128
    const float* __restrict__ bhh,    // C x 2 x 384
    const int* __restrict__ ucl,
    float* __restrict__ outY,         // N x 256
    int N)
{
    const int c = blockIdx.x, d = blockIdx.y;
    const int start = ucl[c];
    const int len = ucl[c + 1] - start;
    const int g = threadIdx.x;        // 0..127

    const float* wbase = Whh + (size_t)(c * 2 + d) * 384 * 128;
    half2_t w0[64], w1[64], w2[64];
    {
        const float2* r0 = (const float2*)(wbase + (size_t)g * 128);
        const float2* r1 = (const float2*)(wbase + (size_t)(g + 128) * 128);
        const float2* r2 = (const float2*)(wbase + (size_t)(g + 256) * 128);
        #pragma unroll
        for (int i = 0; i < 64; i++) {
            float2 a = r0[i];
            w0[i] = half2_t{(_Float16)a.x, (_Float16)a.y};
        }
        #pragma unroll
        for (int i = 0; i < 64; i++) {
            float2 a = r1[i];
            w1[i] = half2_t{(_Float16)a.x, (_Float16)a.y};
        }
        #pragma unroll
        for (int i = 0; i < 64; i++) {
            float2 a = r2[i];
            w2[i] = half2_t{(_Float16)a.x, (_Float16)a.y};
        }
    }
    const float* bb = bhh + (size_t)(c * 2 + d) * 384;
    const float bh0 = bb[g], bh1 = bb[g + 128], bh2 = bb[g + 256];

    __shared__ __align__(16) half2_t hbuf[2][64];
    if (g < 64) { hbuf[0][g] = half2_t{(_Float16)0.f, (_Float16)0.f}; }
    const float* xpb = xp + ((size_t)d * N + start) * 384;
    float* outb = outY + (size_t)start * 256 + d * 128;

    // x pipeline: xa = x(t even), xb = x(t odd)
    float xa0 = xpb[g], xa1 = xpb[g + 128], xa2 = xpb[g + 256];
    const size_t o1 = (size_t)((len > 1) ? 1 : 0) * 384;
    float xb0 = xpb[o1 + g], xb1 = xpb[o1 + g + 128], xb2 = xpb[o1 + g + 256];
    float hcur = 0.f;
    lds_barrier();

#define GRU_SUBSTEP(HP_IDX, HN_IDX, X0, X1, X2, TT)                          \
    {                                                                        \
        const half8_t* __restrict__ hp = (const half8_t*)hbuf[HP_IDX];       \
        _Float16* __restrict__ hn = (_Float16*)hbuf[HN_IDX];                 \
        float a0 = bh0, a1 = bh1, a2 = bh2;                                  \
        half8_t hr[4];                                                       \
        hr[0] = hp[0]; hr[1] = hp[1]; hr[2] = hp[2]; hr[3] = hp[3];          \
        _Pragma("unroll")                                                    \
        for (int i = 0; i < 16; i++) {                                       \
            union { half8_t v; half2_t h2[4]; } u;                           \
            u.v = hr[i & 3];                                                 \
            if (i + 4 < 16) hr[i & 3] = hp[i + 4];  /* keep 4 reads in flight */ \
            _Pragma("unroll")                                                \
            for (int j = 0; j < 4; j++) {                                    \
                a0 = __builtin_amdgcn_fdot2(w0[i * 4 + j], u.h2[j], a0, false);\
                a1 = __builtin_amdgcn_fdot2(w1[i * 4 + j], u.h2[j], a1, false);\
                a2 = __builtin_amdgcn_fdot2(w2[i * 4 + j], u.h2[j], a2, false);\
            }                                                                \
        }                                                                    \
        float r = __fdividef(1.f, 1.f + __expf(-((X0) + a0)));               \
        float z = __fdividef(1.f, 1.f + __expf(-((X1) + a1)));               \
        float pre = (X2) + r * a2;                                           \
        float n = 1.f - __fdividef(2.f, __expf(2.f * pre) + 1.f);            \
        float hnew = (1.f - z) * n + z * hcur;                               \
        hn[g] = (_Float16)hnew;                                              \
        hcur = hnew;                                                         \
        outb[(size_t)(TT) * 256 + g] = hnew;                                 \
    }

    for (int t = 0; t < len; t += 2) {
        // ---- sub-step A: time t (even) ----
        int tpa = (t + 2 < len) ? (t + 2) : (len - 1);
        const float* xra = xpb + (size_t)tpa * 384;
        float ta0 = xra[g], ta1 = xra[g + 128], ta2 = xra[g + 256];
        int ttA = d ? (len - 1 - t) : t;
        GRU_SUBSTEP(0, 1, xa0, xa1, xa2, ttA)
        xa0 = ta0; xa1 = ta1; xa2 = ta2;
        lds_barrier();
        if (t + 1 >= len) break;
        // ---- sub-step B: time t+1 (odd) ----
        int tpb = (t + 3 < len) ? (t + 3) : (len - 1);
        const float* xrb = xpb + (size_t)tpb * 384;
        float tb0 = xrb[g], tb1 = xrb[g + 128], tb2 = xrb[g + 256];
        int ttB = d ? (len - 2 - t) : (t + 1);
        GRU_SUBSTEP(1, 0, xb0, xb1, xb2, ttB)
        xb0 = tb0; xb1 = tb1; xb2 = tb2;
        lds_barrier();
    }
#undef GRU_SUBSTEP
}

// ---------------- 6. head: sigmoid(dot(outY[n], out_W) + b) ----------------
__global__ __launch_bounds__(256) void final_kernel(
    const float* __restrict__ outY,   // N x 256
    const float* __restrict__ outW,   // 256
    const float* __restrict__ outb,   // 1
    float* __restrict__ out, int N)
{
    __shared__ __align__(16) float wsh[256];
    wsh[threadIdx.x] = outW[threadIdx.x];
    __syncthreads();
    const int lane = threadIdx.x & 63;
    const int wave = (blockIdx.x * 256 + threadIdx.x) >> 6;
    const int nw = gridDim.x * 4;
    float4 w4 = *(const float4*)&wsh[lane * 4];
    float b = outb[0];
    for (int n = wave; n < N; n += nw) {
        float4 y = *(const float4*)(outY + (size_t)n * 256 + lane * 4);
        float p = y.x * w4.x + y.y * w4.y + y.z * w4.z + y.w * w4.w;
        #pragma unroll
        for (int off = 32; off > 0; off >>= 1) p += __shfl_down(p, off);
        if (lane == 0) out[n] = 1.f / (1.f + __expf(-(p + b)));
    }
}

extern "C" void kernel_launch(void* const* d_in, const int* in_sizes, int n_in,
                              void* d_out, int out_size, void* d_ws, size_t ws_size,
                              hipStream_t stream)
{
    const float* acbf  = (const float*)d_in[3];
    const float* score = (const float*)d_in[4];
    const float* box   = (const float*)d_in[5];
    const float* orig  = (const float*)d_in[6];
    const int*   ucl   = (const int*)d_in[8];
    const float* aW  = (const float*)d_in[9];
    const float* ab  = (const float*)d_in[10];
    const float* fW  = (const float*)d_in[11];
    const float* fb  = (const float*)d_in[12];
    const float* Wih = (const float*)d_in[13];
    const float* Whh = (const float*)d_in[14];
    const float* bih = (const float*)d_in[15];
    const float* bhh = (const float*)d_in[16];
    const float* oW  = (const float*)d_in[17];
    const float* ob  = (const float*)d_in[18];
    float* out = (float*)d_out;

    const int N = in_sizes[3] / 1024;   // 20640
    const int C = in_sizes[7];          // 80

    // workspace layout (floats): allf N*224 | dec N*128 | xp 2*N*384  (~92.5 MB)
    // outY (N*256) overlaps allf+dec head — both dead once the GRU starts.
    float* ws   = (float*)d_ws;
    float* allf = ws;
    float* dec  = ws + (size_t)N * 224;
    float* xp   = dec + (size_t)N * 128;
    float* outY = ws;

    dim3 blk(256);
    concat_kernel<<<dim3((N * 96 + 255) / 256), blk, 0, stream>>>(score, box, orig, allf, N);
    gemm128_kernel<<<dim3((N + 63) / 64), blk, 0, stream>>>(acbf, 1024, aW, ab, allf, 224, N, 1024, 1);
    gemm128_kernel<<<dim3((N + 63) / 64), blk, 0, stream>>>(allf, 224, fW, fb, dec, 128, N, 224, 1);
    xp_kernel<<<dim3(C, 7, 6), blk, 0, stream>>>(dec, Wih, bih, ucl, xp, N);
    gru_kernel<<<dim3(C, 2), dim3(128), 0, stream>>>(xp, Whh, bhh, ucl, outY, N);
    final_kernel<<<dim3(160), blk, 0, stream>>>(outY, oW, ob, out, N);
}

// Round 6
// 607.791 us; speedup vs baseline: 1.1777x; 1.1440x over previous
//
#include <hip/hip_runtime.h>
#include <hip/hip_bf16.h>
#include <cstdint>

// Encoder_Decoder: C=80 classes, H=128, N=sum(lengths)=20640, L_max=416.
// Phases (all dense GEMMs now f16 MFMA, fp32 accumulate):
//  1) concat extras (f16) into allf16[:,128:224]
//  2) allf16[:,:128] = relu(acbf @ appear_W^T + ab)      MFMA K=1024
//  3) dec16 = relu(allf16 @ feat_W^T + fb)               MFMA K=224
//  4) xp16[d][start+t] = dec16[gather] @ Wih^T + bih     MFMA K=128, per class
//  5) GRU scan per (class,dir): 128 thr x 3 rows, f16 weights + v_dot2
//  6) out[n] = sigmoid(dot(outY[n,:256], out_W) + out_b)

typedef _Float16 half2_t __attribute__((ext_vector_type(2)));
typedef _Float16 half8_t __attribute__((ext_vector_type(8)));
typedef float f32x4 __attribute__((ext_vector_type(4)));

// LDS-only barrier: __syncthreads() drains vmcnt (in-flight global ops);
// cross-thread data here flows only through LDS, lgkmcnt(0) suffices.
__device__ __forceinline__ void lds_barrier() {
    asm volatile("s_waitcnt lgkmcnt(0)\n\ts_barrier" ::: "memory");
}

__device__ __forceinline__ half8_t cvt8(float4 f0, float4 f1) {
    return half8_t{(_Float16)f0.x, (_Float16)f0.y, (_Float16)f0.z, (_Float16)f0.w,
                   (_Float16)f1.x, (_Float16)f1.y, (_Float16)f1.z, (_Float16)f1.w};
}

// ---------------- 1. concat extras (f16) ----------------
__global__ __launch_bounds__(256) void concat_kernel(
    const float* __restrict__ score, const float* __restrict__ box,
    const float* __restrict__ orig, _Float16* __restrict__ allf, int N)
{
    int idx = blockIdx.x * 256 + threadIdx.x;
    int total = N * 96;
    if (idx >= total) return;
    int n = idx / 96, j = idx - n * 96;
    float v;
    if (j < 32)      v = score[(size_t)n * 32 + j];
    else if (j < 64) v = box  [(size_t)n * 32 + j - 32];
    else             v = orig [(size_t)n * 32 + j - 64];
    allf[(size_t)n * 224 + 128 + j] = (_Float16)v;
}

// ---------------- MFMA GEMM: C(N x 128) = act(A(N x K) @ B(128 x K)^T + bias) ----------------
// 256 thr = 4 waves; tile 64 rows x 128 cols; wave = 1 row-tile(16) x 8 col-tiles.
// K-chunk 32. LDS staged in MFMA fragment order (lane-contiguous 16B slots):
//   A slot u = rt*64 + q*16 + m  <- A[n0+rt*16+m][kc*32 + q*8 .. +7]
//   B slot u = ct*64 + q*16 + n  <- B[ct*16+n]  [kc*32 + q*8 .. +7]
// Frag layouts (m89-verified): A/B lane = idx&15 + 16*(k/8); C/D col=lane&15,
// row = 4*(lane>>4) + reg.
template<bool A_F16>
__global__ __launch_bounds__(256) void mfma_gemm_kernel(
    const void* __restrict__ Av, int lda,
    const float* __restrict__ B, int ldb,       // 128 x ldb f32 (ldb >= K)
    const float* __restrict__ bias,
    _Float16* __restrict__ Cc, int ldc,
    int Nrows, int K, int do_relu)
{
    __shared__ __align__(16) _Float16 Asl[256 * 8];   // 4 KB
    __shared__ __align__(16) _Float16 Bsl[512 * 8];   // 8 KB
    const int tid = threadIdx.x;
    const int wave = tid >> 6, lane = tid & 63;
    const int n0 = blockIdx.x * 64;

    // A staging: slot = tid
    const int a_rt = tid >> 6, a_q = (tid >> 4) & 3, a_m = tid & 15;
    int arow = n0 + a_rt * 16 + a_m; if (arow > Nrows - 1) arow = Nrows - 1;
    // B staging: slots tid and tid+256
    const int b_q = (tid >> 4) & 3, b_n = tid & 15;
    const int bcol0 = (tid >> 6) * 16 + b_n;          // ct 0..3
    const int bcol1 = bcol0 + 64;                     // ct 4..7

    f32x4 acc[8] = {};
    half8_t a_st, b_st0, b_st1;

    auto load_chunk = [&](int kc) {
        int k = kc * 32;
        if constexpr (A_F16) {
            const _Float16* A = (const _Float16*)Av;
            a_st = *(const half8_t*)(A + (size_t)arow * lda + k + a_q * 8);
        } else {
            const float* A = (const float*)Av;
            const float4* p = (const float4*)(A + (size_t)arow * lda + k + a_q * 8);
            a_st = cvt8(p[0], p[1]);
        }
        const float4* p0 = (const float4*)(B + (size_t)bcol0 * ldb + k + b_q * 8);
        const float4* p1 = (const float4*)(B + (size_t)bcol1 * ldb + k + b_q * 8);
        b_st0 = cvt8(p0[0], p0[1]);
        b_st1 = cvt8(p1[0], p1[1]);
    };

    load_chunk(0);
    const int nkc = K >> 5;
    for (int kc = 0; kc < nkc; kc++) {
        lds_barrier();                       // prev compute's LDS reads done
        *(half8_t*)(Asl + tid * 8) = a_st;
        *(half8_t*)(Bsl + tid * 8) = b_st0;
        *(half8_t*)(Bsl + (tid + 256) * 8) = b_st1;
        lds_barrier();
        if (kc + 1 < nkc) load_chunk(kc + 1);   // prefetch under MFMA
        half8_t af = *(const half8_t*)(Asl + (wave * 64 + lane) * 8);
        #pragma unroll
        for (int ct = 0; ct < 8; ct++) {
            half8_t bf = *(const half8_t*)(Bsl + (ct * 64 + lane) * 8);
            acc[ct] = __builtin_amdgcn_mfma_f32_16x16x32_f16(af, bf, acc[ct], 0, 0, 0);
        }
    }

    const int crow = n0 + wave * 16 + (lane >> 4) * 4;
    const int ccol = lane & 15;
    #pragma unroll
    for (int ct = 0; ct < 8; ct++) {
        int col = ct * 16 + ccol;
        float bv = bias[col];
        #pragma unroll
        for (int reg = 0; reg < 4; reg++) {
            int row = crow + reg;
            if (row >= Nrows) continue;
            float v = acc[ct][reg] + bv;
            if (do_relu) v = v > 0.f ? v : 0.f;
            Cc[(size_t)row * ldc + col] = (_Float16)v;
        }
    }
}

// ---------------- 4. Xp per-class MFMA GEMM (K=128) with direction gather ----------------
__global__ __launch_bounds__(256) void mfma_xp_kernel(
    const _Float16* __restrict__ dec, // N x 128 f16
    const float* __restrict__ Wih,    // C x 2 x 384 x 128 f32
    const float* __restrict__ bih,    // C x 2 x 384 f32
    const int* __restrict__ ucl,
    _Float16* __restrict__ xp,        // 2 x N x 384 f16
    int N)
{
    const int c = blockIdx.x;
    const int tile = blockIdx.y;
    const int d = blockIdx.z / 3, mt = blockIdx.z % 3;
    const int start = ucl[c];
    const int len = ucl[c + 1] - start;
    const int t0 = tile * 64;
    if (t0 >= len) return;

    __shared__ __align__(16) _Float16 Asl[256 * 8];
    __shared__ __align__(16) _Float16 Bsl[512 * 8];
    const int tid = threadIdx.x;
    const int wave = tid >> 6, lane = tid & 63;

    const int a_rt = tid >> 6, a_q = (tid >> 4) & 3, a_m = tid & 15;
    int t = t0 + a_rt * 16 + a_m; if (t > len - 1) t = len - 1;
    const int srow = start + (d ? (len - 1 - t) : t);

    const float* Bb = Wih + ((size_t)(c * 2 + d) * 384 + mt * 128) * 128;
    const int b_q = (tid >> 4) & 3, b_n = tid & 15;
    const int bcol0 = (tid >> 6) * 16 + b_n;
    const int bcol1 = bcol0 + 64;

    f32x4 acc[8] = {};
    half8_t a_st, b_st0, b_st1;

    auto load_chunk = [&](int kc) {
        int k = kc * 32;
        a_st = *(const half8_t*)(dec + (size_t)srow * 128 + k + a_q * 8);
        const float4* p0 = (const float4*)(Bb + (size_t)bcol0 * 128 + k + b_q * 8);
        const float4* p1 = (const float4*)(Bb + (size_t)bcol1 * 128 + k + b_q * 8);
        b_st0 = cvt8(p0[0], p0[1]);
        b_st1 = cvt8(p1[0], p1[1]);
    };

    load_chunk(0);
    for (int kc = 0; kc < 4; kc++) {
        lds_barrier();
        *(half8_t*)(Asl + tid * 8) = a_st;
        *(half8_t*)(Bsl + tid * 8) = b_st0;
        *(half8_t*)(Bsl + (tid + 256) * 8) = b_st1;
        lds_barrier();
        if (kc + 1 < 4) load_chunk(kc + 1);
        half8_t af = *(const half8_t*)(Asl + (wave * 64 + lane) * 8);
        #pragma unroll
        for (int ct = 0; ct < 8; ct++) {
            half8_t bf = *(const half8_t*)(Bsl + (ct * 64 + lane) * 8);
            acc[ct] = __builtin_amdgcn_mfma_f32_16x16x32_f16(af, bf, acc[ct], 0, 0, 0);
        }
    }

    const float* bias = bih + (size_t)(c * 2 + d) * 384 + mt * 128;
    const int trow = t0 + wave * 16 + (lane >> 4) * 4;
    const int ccol = lane & 15;
    #pragma unroll
    for (int ct = 0; ct < 8; ct++) {
        int col = ct * 16 + ccol;
        float bv = bias[col];
        #pragma unroll
        for (int reg = 0; reg < 4; reg++) {
            int tt = trow + reg;
            if (tt >= len) continue;
            float v = acc[ct][reg] + bv;
            xp[((size_t)d * N + start + tt) * 384 + mt * 128 + col] = (_Float16)v;
        }
    }
}

// ---------------- 5. GRU scan ----------------
// One block per (class,dir), 128 threads; thread g owns gate rows {g,g+128,g+256}.
// f16 weights in 192 VGPRs, v_dot2 matvec, f16 h via 512B LDS double-buffer,
// lgkmcnt-only barrier, 2-step-deep x prefetch. (~1630 cyc/step plateau.)
__global__ __launch_bounds__(128, 1) void gru_kernel(
    const _Float16* __restrict__ xp,  // 2 x N x 384 f16
    const float* __restrict__ Whh,    // C x 2 x 384 x 128
    const float* __restrict__ bhh,    // C x 2 x 384
    const int* __restrict__ ucl,
    float* __restrict__ outY,         // N x 256 f32
    int N)
{
    const int c = blockIdx.x, d = blockIdx.y;
    const int start = ucl[c];
    const int len = ucl[c + 1] - start;
    const int g = threadIdx.x;        // 0..127

    const float* wbase = Whh + (size_t)(c * 2 + d) * 384 * 128;
    half2_t w0[64], w1[64], w2[64];
    {
        const float2* r0 = (const float2*)(wbase + (size_t)g * 128);
        const float2* r1 = (const float2*)(wbase + (size_t)(g + 128) * 128);
        const float2* r2 = (const float2*)(wbase + (size_t)(g + 256) * 128);
        #pragma unroll
        for (int i = 0; i < 64; i++) {
            float2 a = r0[i];
            w0[i] = half2_t{(_Float16)a.x, (_Float16)a.y};
        }
        #pragma unroll
        for (int i = 0; i < 64; i++) {
            float2 a = r1[i];
            w1[i] = half2_t{(_Float16)a.x, (_Float16)a.y};
        }
        #pragma unroll
        for (int i = 0; i < 64; i++) {
            float2 a = r2[i];
            w2[i] = half2_t{(_Float16)a.x, (_Float16)a.y};
        }
    }
    const float* bb = bhh + (size_t)(c * 2 + d) * 384;
    const float bh0 = bb[g], bh1 = bb[g + 128], bh2 = bb[g + 256];

    __shared__ __align__(16) half2_t hbuf[2][64];
    if (g < 64) { hbuf[0][g] = half2_t{(_Float16)0.f, (_Float16)0.f}; }
    const _Float16* xpb = xp + ((size_t)d * N + start) * 384;
    float* outb = outY + (size_t)start * 256 + d * 128;

    float xa0 = (float)xpb[g], xa1 = (float)xpb[g + 128], xa2 = (float)xpb[g + 256];
    const size_t o1 = (size_t)((len > 1) ? 1 : 0) * 384;
    float xb0 = (float)xpb[o1 + g], xb1 = (float)xpb[o1 + g + 128], xb2 = (float)xpb[o1 + g + 256];
    float hcur = 0.f;
    lds_barrier();

#define GRU_SUBSTEP(HP_IDX, HN_IDX, X0, X1, X2, TT)                          \
    {                                                                        \
        const half8_t* __restrict__ hp = (const half8_t*)hbuf[HP_IDX];       \
        _Float16* __restrict__ hn = (_Float16*)hbuf[HN_IDX];                 \
        float a0 = bh0, a1 = bh1, a2 = bh2;                                  \
        half8_t hr[4];                                                       \
        hr[0] = hp[0]; hr[1] = hp[1]; hr[2] = hp[2]; hr[3] = hp[3];          \
        _Pragma("unroll")                                                    \
        for (int i = 0; i < 16; i++) {                                       \
            union { half8_t v; half2_t h2[4]; } u;                           \
            u.v = hr[i & 3];                                                 \
            if (i + 4 < 16) hr[i & 3] = hp[i + 4];                           \
            _Pragma("unroll")                                                \
            for (int j = 0; j < 4; j++) {                                    \
                a0 = __builtin_amdgcn_fdot2(w0[i * 4 + j], u.h2[j], a0, false);\
                a1 = __builtin_amdgcn_fdot2(w1[i * 4 + j], u.h2[j], a1, false);\
                a2 = __builtin_amdgcn_fdot2(w2[i * 4 + j], u.h2[j], a2, false);\
            }                                                                \
        }                                                                    \
        float r = __fdividef(1.f, 1.f + __expf(-((X0) + a0)));               \
        float z = __fdividef(1.f, 1.f + __expf(-((X1) + a1)));               \
        float pre = (X2) + r * a2;                                           \
        float n = 1.f - __fdividef(2.f, __expf(2.f * pre) + 1.f);            \
        float hnew = (1.f - z) * n + z * hcur;                               \
        hn[g] = (_Float16)hnew;                                              \
        hcur = hnew;                                                         \
        outb[(size_t)(TT) * 256 + g] = hnew;                                 \
    }

    for (int t = 0; t < len; t += 2) {
        int tpa = (t + 2 < len) ? (t + 2) : (len - 1);
        const _Float16* xra = xpb + (size_t)tpa * 384;
        float ta0 = (float)xra[g], ta1 = (float)xra[g + 128], ta2 = (float)xra[g + 256];
        int ttA = d ? (len - 1 - t) : t;
        GRU_SUBSTEP(0, 1, xa0, xa1, xa2, ttA)
        xa0 = ta0; xa1 = ta1; xa2 = ta2;
        lds_barrier();
        if (t + 1 >= len) break;
        int tpb = (t + 3 < len) ? (t + 3) : (len - 1);
        const _Float16* xrb = xpb + (size_t)tpb * 384;
        float tb0 = (float)xrb[g], tb1 = (float)xrb[g + 128], tb2 = (float)xrb[g + 256];
        int ttB = d ? (len - 2 - t) : (t + 1);
        GRU_SUBSTEP(1, 0, xb0, xb1, xb2, ttB)
        xb0 = tb0; xb1 = tb1; xb2 = tb2;
        lds_barrier();
    }
#undef GRU_SUBSTEP
}

// ---------------- 6. head: sigmoid(dot(outY[n], out_W) + b) ----------------
__global__ __launch_bounds__(256) void final_kernel(
    const float* __restrict__ outY,   // N x 256
    const float* __restrict__ outW,   // 256
    const float* __restrict__ outb,   // 1
    float* __restrict__ out, int N)
{
    __shared__ __align__(16) float wsh[256];
    wsh[threadIdx.x] = outW[threadIdx.x];
    __syncthreads();
    const int lane = threadIdx.x & 63;
    const int wave = (blockIdx.x * 256 + threadIdx.x) >> 6;
    const int nw = gridDim.x * 4;
    float4 w4 = *(const float4*)&wsh[lane * 4];
    float b = outb[0];
    for (int n = wave; n < N; n += nw) {
        float4 y = *(const float4*)(outY + (size_t)n * 256 + lane * 4);
        float p = y.x * w4.x + y.y * w4.y + y.z * w4.z + y.w * w4.w;
        #pragma unroll
        for (int off = 32; off > 0; off >>= 1) p += __shfl_down(p, off);
        if (lane == 0) out[n] = 1.f / (1.f + __expf(-(p + b)));
    }
}

extern "C" void kernel_launch(void* const* d_in, const int* in_sizes, int n_in,
                              void* d_out, int out_size, void* d_ws, size_t ws_size,
                              hipStream_t stream)
{
    const float* acbf  = (const float*)d_in[3];
    const float* score = (const float*)d_in[4];
    const float* box   = (const float*)d_in[5];
    const float* orig  = (const float*)d_in[6];
    const int*   ucl   = (const int*)d_in[8];
    const float* aW  = (const float*)d_in[9];
    const float* ab  = (const float*)d_in[10];
    const float* fW  = (const float*)d_in[11];
    const float* fb  = (const float*)d_in[12];
    const float* Wih = (const float*)d_in[13];
    const float* Whh = (const float*)d_in[14];
    const float* bih = (const float*)d_in[15];
    const float* bhh = (const float*)d_in[16];
    const float* oW  = (const float*)d_in[17];
    const float* ob  = (const float*)d_in[18];
    float* out = (float*)d_out;

    const int N = in_sizes[3] / 1024;   // 20640
    const int C = in_sizes[7];          // 80

    // workspace: allf16 N*224 | dec16 N*128 | xp16 2*N*384 | outY f32 N*256  (~67 MB)
    _Float16* allf16 = (_Float16*)d_ws;
    _Float16* dec16  = allf16 + (size_t)N * 224;
    _Float16* xp16   = dec16 + (size_t)N * 128;
    float*    outY   = (float*)(xp16 + (size_t)2 * N * 384);

    dim3 blk(256);
    const int rowblocks = (N + 63) / 64;
    concat_kernel<<<dim3((N * 96 + 255) / 256), blk, 0, stream>>>(score, box, orig, allf16, N);
    mfma_gemm_kernel<false><<<dim3(rowblocks), blk, 0, stream>>>(
        (const void*)acbf, 1024, aW, 1024, ab, allf16, 224, N, 1024, 1);
    mfma_gemm_kernel<true><<<dim3(rowblocks), blk, 0, stream>>>(
        (const void*)allf16, 224, fW, 224, fb, dec16, 128, N, 224, 1);
    mfma_xp_kernel<<<dim3(C, 7, 6), blk, 0, stream>>>(dec16, Wih, bih, ucl, xp16, N);
    gru_kernel<<<dim3(C, 2), dim3(128), 0, stream>>>(xp16, Whh, bhh, ucl, outY, N);
    final_kernel<<<dim3(160), blk, 0, stream>>>(outY, oW, ob, out, N);
}